// Round 2
// baseline (2253.055 us; speedup 1.0000x reference)
//
#include <hip/hip_runtime.h>
#include <hip/hip_bf16.h>

typedef __hip_bfloat16 bf16;

#define BB 512
#define SS 512
#define EE 20
#define H1C 30
#define H2C 50
#define G1C 120
#define G2C 200
#define NTC 45

__device__ __forceinline__ float b2f(bf16 v) { return __bfloat162float(v); }
__device__ __forceinline__ float sigf(float v) { return 1.0f / (1.0f + __expf(-v)); }
__device__ __forceinline__ float tanh_(float v) { return 2.0f / (1.0f + __expf(-2.0f * v)) - 1.0f; }

// dual-dtype global load: f32 buffers vs bf16 buffers (detected at runtime)
__device__ __forceinline__ float ldG(const void* p, int i, int f32) {
    if (f32) return ((const float*)p)[i];
    return __bfloat162float(((const bf16*)p)[i]);
}
__device__ __forceinline__ int ldTok(const void* x, int i, int x64) {
    const int* xi = (const int*)x;
    return x64 ? xi[2 * i] : xi[i];   // little-endian: low word of int64
}

// ---------------- dtype detector: flags[0]=is_f32, flags[1]=is_x_int64 ----------------
__global__ void detect_kernel(const void* bih, const void* x, int* flags) {
    if (threadIdx.x == 0 && blockIdx.x == 0) {
        const unsigned short* u = (const unsigned short*)bih;
        int isf = 0;
        for (int i = 0; i < 120; i++) {
            float v = fabsf(__uint_as_float(((unsigned)u[i]) << 16));
            if (!(v < 16.0f)) isf = 1;   // catches big values, Inf, NaN
        }
        flags[0] = isf;
        const int* xi = (const int*)x;
        int orv = 0;
        for (int i = 1; i < 32; i += 2) orv |= xi[i];
        flags[1] = (orv == 0) ? 1 : 0;
    }
}

// ---------------- Layer 1: fused embed + LSTM recurrence, both directions ----------------
// grid 256: wg>>7 = dir (0 fwd, 1 bwd), (wg&127)*4 = batch rows. block 128.
// hs layout: (batch j, time t, H1), bf16.
__global__ __launch_bounds__(128) void lstm1_kernel(
    const void* __restrict__ x,
    const void* __restrict__ emb_f, const void* __restrict__ emb_b,
    const void* __restrict__ h0_f, const void* __restrict__ c0_f,
    const void* __restrict__ Wih_f, const void* __restrict__ Whh_f,
    const void* __restrict__ bih_f, const void* __restrict__ bhh_f,
    const void* __restrict__ h0_b, const void* __restrict__ c0_b,
    const void* __restrict__ Wih_b, const void* __restrict__ Whh_b,
    const void* __restrict__ bih_b, const void* __restrict__ bhh_b,
    bf16* __restrict__ hsf, bf16* __restrict__ hsb,
    const int* __restrict__ flags)
{
    const int f32 = flags[0];
    const int x64 = flags[1];
    const int wg  = blockIdx.x;
    const int dir = wg >> 7;
    const int j0  = (wg & 127) << 2;
    const int tid = threadIdx.x;

    const void* emb = dir ? emb_b : emb_f;
    const void* h0  = dir ? h0_b  : h0_f;
    const void* c0  = dir ? c0_b  : c0_f;
    const void* Wih = dir ? Wih_b : Wih_f;
    const void* Whh = dir ? Whh_b : Whh_f;
    const void* bih = dir ? bih_b : bih_f;
    const void* bhh = dir ? bhh_b : bhh_f;
    bf16* hs = dir ? hsb : hsf;

    __shared__ __align__(16) float xh[EE + H1C][4];   // k<20: emb(x); k in [20,50): h
    __shared__ float G[4][G1C + 9];                    // gates, padded

    float wx[EE], wh[H1C], bias = 0.f;
    if (tid < G1C) {
        #pragma unroll
        for (int e = 0; e < EE; e++)  wx[e] = ldG(Wih, tid * EE + e, f32);
        #pragma unroll
        for (int k = 0; k < H1C; k++) wh[k] = ldG(Whh, tid * H1C + k, f32);
        bias = ldG(bih, tid, f32) + ldG(bhh, tid, f32);
    }

    const int pr = tid / H1C, pm = tid - pr * H1C;     // pointwise role (tid<120)
    float creg = 0.f;
    if (tid < 4 * H1C) {
        creg = ldG(c0, (j0 + pr) * H1C + pm, f32);
        xh[EE + pm][pr] = ldG(h0, (j0 + pr) * H1C + pm, f32);
    }

    const int lr = tid / EE, le = tid - lr * EE;       // loader role (tid<80)
    const int t0 = dir ? (SS - 1) : 0;
    const int dt = dir ? -1 : 1;
    float xe = 0.f;
    if (tid < 4 * EE) {
        int tok = ldTok(x, (j0 + lr) * SS + t0, x64);
        xe = ldG(emb, tok * EE + le, f32);
    }

    for (int it = 0; it < SS; it++) {
        const int t = t0 + dt * it;
        if (tid < 4 * EE) xh[le][lr] = xe;
        __syncthreads();
        // prefetch next step's embedding (token stream is recurrence-free)
        if (tid < 4 * EE && it + 1 < SS) {
            int tok = ldTok(x, (j0 + lr) * SS + (t + dt), x64);
            xe = ldG(emb, tok * EE + le, f32);
        }
        if (tid < G1C) {
            float a0 = bias, a1 = bias, a2 = bias, a3 = bias;
            #pragma unroll
            for (int e = 0; e < EE; e++) {
                float4 v = *(const float4*)&xh[e][0];
                a0 += v.x * wx[e]; a1 += v.y * wx[e]; a2 += v.z * wx[e]; a3 += v.w * wx[e];
            }
            #pragma unroll
            for (int k = 0; k < H1C; k++) {
                float4 v = *(const float4*)&xh[EE + k][0];
                a0 += v.x * wh[k]; a1 += v.y * wh[k]; a2 += v.z * wh[k]; a3 += v.w * wh[k];
            }
            G[0][tid] = a0; G[1][tid] = a1; G[2][tid] = a2; G[3][tid] = a3;
        }
        __syncthreads();
        if (tid < 4 * H1C) {
            float gi = G[pr][pm], gf = G[pr][H1C + pm];
            float gg = G[pr][2 * H1C + pm], go = G[pr][3 * H1C + pm];
            creg = sigf(gf) * creg + sigf(gi) * tanh_(gg);
            float h = sigf(go) * tanh_(creg);
            xh[EE + pm][pr] = h;
            hs[(size_t)(j0 + pr) * (SS * H1C) + (size_t)t * H1C + pm] = __float2bfloat16(h);
        }
    }
}

// ---------------- Layer 2: fused Wih·x + LSTM recurrence, both directions ----------------
// WG owns 4 layer-2 batch rows (= l1 first axis), loops over layer-2 time (= l1 second axis).
// x_t(p, a) = concat( hs1f[batch=a][time=p], hs1b[batch=a][time=S-1-p] ).
__global__ __launch_bounds__(256) void lstm2_kernel(
    const bf16* __restrict__ hs1f, const bf16* __restrict__ hs1b,
    const void* __restrict__ h0_f, const void* __restrict__ c0_f,
    const void* __restrict__ Wih_f, const void* __restrict__ Whh_f,
    const void* __restrict__ bih_f, const void* __restrict__ bhh_f,
    const void* __restrict__ h0_b, const void* __restrict__ c0_b,
    const void* __restrict__ Wih_b, const void* __restrict__ Whh_b,
    const void* __restrict__ bih_b, const void* __restrict__ bhh_b,
    bf16* __restrict__ hsf, bf16* __restrict__ hsb,
    const int* __restrict__ flags)
{
    const int f32 = flags[0];
    const int wg  = blockIdx.x;
    const int dir = wg >> 7;
    const int cb  = (wg & 127) << 2;   // layer-2 batch rows cb..cb+3
    const int tid = threadIdx.x;

    const void* h0  = dir ? h0_b  : h0_f;
    const void* c0  = dir ? c0_b  : c0_f;
    const void* Wih = dir ? Wih_b : Wih_f;
    const void* Whh = dir ? Whh_b : Whh_f;
    const void* bih = dir ? bih_b : bih_f;
    const void* bhh = dir ? bhh_b : bhh_f;
    bf16* hs = dir ? hsb : hsf;

    __shared__ __align__(16) float xh[2 * H1C + H2C][4];   // k<60: x; [60,110): h
    __shared__ float G[4][G2C + 9];

    float wx[2 * H1C], wh[H2C], bias = 0.f;
    if (tid < G2C) {
        #pragma unroll
        for (int e = 0; e < 2 * H1C; e++) wx[e] = ldG(Wih, tid * (2 * H1C) + e, f32);
        #pragma unroll
        for (int k = 0; k < H2C; k++)     wh[k] = ldG(Whh, tid * H2C + k, f32);
        bias = ldG(bih, tid, f32) + ldG(bhh, tid, f32);
    }

    const int pr = tid / H2C, pm = tid - pr * H2C;         // pointwise role (tid<200)
    float creg = 0.f;
    if (tid < 4 * H2C) {
        creg = ldG(c0, (cb + pr) * H2C + pm, f32);
        xh[2 * H1C + pm][pr] = ldG(h0, (cb + pr) * H2C + pm, f32);
    }

    const int fr = tid / H1C, fm = tid - fr * H1C;         // f-loader (tid<120)
    const int bi = tid - 128;
    const int br = (bi >= 0) ? (bi / H1C) : 0, bm = bi - br * H1C;  // b-loader (128<=tid<248)
    const int t0 = dir ? (SS - 1) : 0;
    const int dt = dir ? -1 : 1;
    float xf = 0.f, xb = 0.f;
    if (tid < 4 * H1C)
        xf = b2f(hs1f[(size_t)t0 * (SS * H1C) + (size_t)(cb + fr) * H1C + fm]);
    if (bi >= 0 && bi < 4 * H1C)
        xb = b2f(hs1b[(size_t)t0 * (SS * H1C) + (size_t)(SS - 1 - (cb + br)) * H1C + bm]);

    for (int it = 0; it < SS; it++) {
        const int a = t0 + dt * it;
        if (tid < 4 * H1C) xh[fm][fr] = xf;
        if (bi >= 0 && bi < 4 * H1C) xh[H1C + bm][br] = xb;
        __syncthreads();
        if (it + 1 < SS) {
            const int an = a + dt;
            if (tid < 4 * H1C)
                xf = b2f(hs1f[(size_t)an * (SS * H1C) + (size_t)(cb + fr) * H1C + fm]);
            if (bi >= 0 && bi < 4 * H1C)
                xb = b2f(hs1b[(size_t)an * (SS * H1C) + (size_t)(SS - 1 - (cb + br)) * H1C + bm]);
        }
        if (tid < G2C) {
            float a0 = bias, a1 = bias, a2 = bias, a3 = bias;
            #pragma unroll
            for (int k = 0; k < 2 * H1C; k++) {
                float4 v = *(const float4*)&xh[k][0];
                a0 += v.x * wx[k]; a1 += v.y * wx[k]; a2 += v.z * wx[k]; a3 += v.w * wx[k];
            }
            #pragma unroll
            for (int k = 0; k < H2C; k++) {
                float4 v = *(const float4*)&xh[2 * H1C + k][0];
                a0 += v.x * wh[k]; a1 += v.y * wh[k]; a2 += v.z * wh[k]; a3 += v.w * wh[k];
            }
            G[0][tid] = a0; G[1][tid] = a1; G[2][tid] = a2; G[3][tid] = a3;
        }
        __syncthreads();
        if (tid < 4 * H2C) {
            float gi = G[pr][pm], gf = G[pr][H2C + pm];
            float gg = G[pr][2 * H2C + pm], go = G[pr][3 * H2C + pm];
            creg = sigf(gf) * creg + sigf(gi) * tanh_(gg);
            float h = sigf(go) * tanh_(creg);
            xh[2 * H1C + pm][pr] = h;
            // hs2 layout: (time a, row p, H2)
            hs[(size_t)a * (SS * H2C) + (size_t)(cb + pr) * H2C + pm] = __float2bfloat16(h);
        }
    }
}

// ---------------- Final linear ----------------
// out[i,j,:] = concat( hs2f[time=i][row=j], hs2b[time=S-1-i][row=j] ) @ lin_w.T + lin_b
__global__ __launch_bounds__(256) void lin_kernel(
    const bf16* __restrict__ hs2f, const bf16* __restrict__ hs2b,
    const void* __restrict__ lw, const void* __restrict__ lb,
    void* __restrict__ out, const int* __restrict__ flags)
{
    const int f32 = flags[0];
    __shared__ __align__(16) float lwS[NTC][100];
    __shared__ float lbS[64];
    __shared__ __align__(16) float xv[4][100];
    const int tid = threadIdx.x;
    for (int i = tid; i < NTC * 100; i += 256) lwS[i / 100][i % 100] = ldG(lw, i, f32);
    if (tid < NTC) lbS[tid] = ldG(lb, tid, f32);
    __syncthreads();
    const int grp = tid >> 6, lane = tid & 63;
    const int PPG = 8;
    for (int p = 0; p < PPG; p++) {
        size_t pair = (size_t)blockIdx.x * (4 * PPG) + (size_t)grp * PPG + p;
        const int i = (int)(pair >> 9), j = (int)(pair & 511);
        __syncthreads();
        if (lane < H2C) {
            xv[grp][lane]       = b2f(hs2f[(size_t)i * (SS * H2C) + (size_t)j * H2C + lane]);
            xv[grp][H2C + lane] = b2f(hs2b[(size_t)(SS - 1 - i) * (SS * H2C) + (size_t)j * H2C + lane]);
        }
        __syncthreads();
        if (lane < NTC) {
            float acc = lbS[lane];
            #pragma unroll
            for (int k = 0; k < 100; k += 4) {
                float4 w = *(const float4*)&lwS[lane][k];
                float4 v = *(const float4*)&xv[grp][k];
                acc += w.x * v.x + w.y * v.y + w.z * v.z + w.w * v.w;
            }
            if (f32) ((float*)out)[pair * NTC + lane] = acc;
            else     ((bf16*)out)[pair * NTC + lane] = __float2bfloat16(acc);
        }
    }
}

extern "C" void kernel_launch(void* const* d_in, const int* in_sizes, int n_in,
                              void* d_out, int out_size, void* d_ws, size_t ws_size,
                              hipStream_t stream)
{
    const void* x      = d_in[0];
    const void* emb_f1 = d_in[1];
    const void* emb_b1 = d_in[2];
    const void* h0_f1  = d_in[3];
    const void* c0_f1  = d_in[4];
    const void* Wih_f1 = d_in[5];
    const void* Whh_f1 = d_in[6];
    const void* bih_f1 = d_in[7];
    const void* bhh_f1 = d_in[8];
    const void* h0_b1  = d_in[9];
    const void* c0_b1  = d_in[10];
    const void* Wih_b1 = d_in[11];
    const void* Whh_b1 = d_in[12];
    const void* bih_b1 = d_in[13];
    const void* bhh_b1 = d_in[14];
    const void* h0_f2  = d_in[15];
    const void* c0_f2  = d_in[16];
    const void* Wih_f2 = d_in[17];
    const void* Whh_f2 = d_in[18];
    const void* bih_f2 = d_in[19];
    const void* bhh_f2 = d_in[20];
    const void* h0_b2  = d_in[21];
    const void* c0_b2  = d_in[22];
    const void* Wih_b2 = d_in[23];
    const void* Whh_b2 = d_in[24];
    const void* bih_b2 = d_in[25];
    const void* bhh_b2 = d_in[26];
    const void* lin_w  = d_in[27];
    const void* lin_b  = d_in[28];

    // ws layout: [flags: 256B] | hs1f | hs1b | hs2f | hs2b  (bf16, ~84 MB)
    int* flags = (int*)d_ws;
    bf16* hs1f = (bf16*)((char*)d_ws + 256);
    bf16* hs1b = hs1f + (size_t)BB * SS * H1C;
    bf16* hs2f = hs1b + (size_t)BB * SS * H1C;
    bf16* hs2b = hs2f + (size_t)BB * SS * H2C;

    detect_kernel<<<1, 64, 0, stream>>>(bih_f1, x, flags);
    lstm1_kernel<<<256, 128, 0, stream>>>(x, emb_f1, emb_b1,
        h0_f1, c0_f1, Wih_f1, Whh_f1, bih_f1, bhh_f1,
        h0_b1, c0_b1, Wih_b1, Whh_b1, bih_b1, bhh_b1, hs1f, hs1b, flags);
    lstm2_kernel<<<256, 256, 0, stream>>>(hs1f, hs1b,
        h0_f2, c0_f2, Wih_f2, Whh_f2, bih_f2, bhh_f2,
        h0_b2, c0_b2, Wih_b2, Whh_b2, bih_b2, bhh_b2, hs2f, hs2b, flags);
    lin_kernel<<<(BB * SS) / 32, 256, 0, stream>>>(hs2f, hs2b, lin_w, lin_b, d_out, flags);
}

// Round 3
// 1489.456 us; speedup vs baseline: 1.5127x; 1.5127x over previous
//
#include <hip/hip_runtime.h>
#include <hip/hip_bf16.h>

typedef __hip_bfloat16 bf16;
typedef __attribute__((ext_vector_type(8))) short short8;
typedef __attribute__((ext_vector_type(4))) float float4v;
typedef unsigned short ushort_t;

#define BB 512
#define SS 512
#define EE 20
#define H1C 30
#define H2C 50
#define NTC 45

__device__ __forceinline__ float sigf(float v) { return 1.0f / (1.0f + __expf(-v)); }
__device__ __forceinline__ float tanh_(float v) { return 2.0f / (1.0f + __expf(-2.0f * v)) - 1.0f; }

__device__ __forceinline__ ushort_t f2bf(float f) {           // RNE f32->bf16 bits
    unsigned u = __float_as_uint(f);
    unsigned r = u + 0x7FFFu + ((u >> 16) & 1u);
    return (ushort_t)(r >> 16);
}
__device__ __forceinline__ float bf2f(ushort_t s) { return __uint_as_float(((unsigned)s) << 16); }

// dual-dtype global load: f32 buffers vs bf16 buffers (detected at runtime)
__device__ __forceinline__ float ldG(const void* p, int i, int f32) {
    if (f32) return ((const float*)p)[i];
    return bf2f(((const ushort_t*)p)[i]);
}
__device__ __forceinline__ int ldTok(const void* x, int i, int x64) {
    const int* xi = (const int*)x;
    return x64 ? xi[2 * i] : xi[i];
}

// ---------------- dtype detector: flags[0]=is_f32, flags[1]=is_x_int64 ----------------
__global__ void detect_kernel(const void* bih, const void* x, int* flags) {
    if (threadIdx.x == 0 && blockIdx.x == 0) {
        const ushort_t* u = (const ushort_t*)bih;
        int isf = 0;
        for (int i = 0; i < 120; i++) {
            float v = fabsf(bf2f(u[i]));
            if (!(v < 16.0f)) isf = 1;
        }
        flags[0] = isf;
        const int* xi = (const int*)x;
        int orv = 0;
        for (int i = 1; i < 32; i += 2) orv |= xi[i];
        flags[1] = (orv == 0) ? 1 : 0;
    }
}

// =========================================================================================
// Layer 1: MFMA LSTM. 128 thr (2 waves), 4 batch rows/WG, grid 256 (dir * 128 j-blocks).
// K layout (pad 64): k<20 = emb(x), 20..49 = h, 50..63 = 0.  N: n = g*32 + mcol, wave w
// owns mcol block [16w,16w+16): acc tiles g=0..3 are exactly i,f,g,o for its cells.
// Af[buf][kt][lane=kg*16+row][j] : A-fragment-order LDS (lane reads its own 16B).
// =========================================================================================
__global__ __launch_bounds__(128) void lstm1_kernel(
    const void* __restrict__ x,
    const void* __restrict__ emb_f, const void* __restrict__ emb_b,
    const void* __restrict__ h0_f, const void* __restrict__ c0_f,
    const void* __restrict__ Wih_f, const void* __restrict__ Whh_f,
    const void* __restrict__ bih_f, const void* __restrict__ bhh_f,
    const void* __restrict__ h0_b, const void* __restrict__ c0_b,
    const void* __restrict__ Wih_b, const void* __restrict__ Whh_b,
    const void* __restrict__ bih_b, const void* __restrict__ bhh_b,
    ushort_t* __restrict__ hsf, ushort_t* __restrict__ hsb,
    const int* __restrict__ flags)
{
    const int f32 = flags[0], x64 = flags[1];
    const int wg = blockIdx.x, dir = wg >> 7, j0 = (wg & 127) << 2, tid = threadIdx.x;
    const int wave = tid >> 6, lane = tid & 63, li = lane & 15, kq = lane >> 4;

    const void* emb = dir ? emb_b : emb_f;
    const void* h0  = dir ? h0_b  : h0_f;
    const void* c0  = dir ? c0_b  : c0_f;
    const void* Wih = dir ? Wih_b : Wih_f;
    const void* Whh = dir ? Whh_b : Whh_f;
    const void* bih = dir ? bih_b : bih_f;
    const void* bhh = dir ? bhh_b : bhh_f;
    ushort_t* hs = dir ? hsb : hsf;

    __shared__ __align__(16) ushort_t Af[2][2][64][8];
    __shared__ int toks[4][SS];

    for (int idx = tid; idx < 4 * SS; idx += 128) {
        int r = idx >> 9, t = idx & (SS - 1);
        toks[r][t] = ldTok(x, (j0 + r) * SS + t, x64);
    }
    for (int idx = tid; idx < 2 * 2 * 64 * 8; idx += 128) ((ushort_t*)Af)[idx] = 0;

    // B fragments (weights, hi+lo bf16 split), held in registers for the whole kernel
    const int mcol = wave * 16 + li;
    short8 bhi[4][2], blo[4][2];
    float bias_g[4];
    #pragma unroll
    for (int g = 0; g < 4; g++) {
        const int wrow = g * H1C + mcol;
        const bool nok = mcol < H1C;
        bias_g[g] = nok ? (ldG(bih, wrow, f32) + ldG(bhh, wrow, f32)) : 0.f;
        #pragma unroll
        for (int kt = 0; kt < 2; kt++) {
            short8 hi, lo;
            #pragma unroll
            for (int j = 0; j < 8; j++) {
                int k = kt * 32 + kq * 8 + j;
                float w = 0.f;
                if (nok) {
                    if (k < EE) w = ldG(Wih, wrow * EE + k, f32);
                    else if (k < EE + H1C) w = ldG(Whh, wrow * H1C + (k - EE), f32);
                }
                ushort_t h = f2bf(w);
                hi[j] = (short)h;
                lo[j] = (short)f2bf(w - bf2f(h));
            }
            bhi[g][kt] = hi; blo[g][kt] = lo;
        }
    }

    const int t0 = dir ? SS - 1 : 0, dt = dir ? -1 : 1;
    const bool pw = (lane < 16) && (mcol < H1C) && (wave < 2);
    float creg[4];
    ushort_t hbits[4];
    const int kx = tid >> 2, lr = tid & 3;
    const bool xl = tid < 4 * EE;
    ushort_t xv = 0, xnv = 0;

    __syncthreads();   // Af zero + toks ready

    if (pw) {
        #pragma unroll
        for (int r = 0; r < 4; r++) {
            creg[r]  = ldG(c0, (j0 + r) * H1C + mcol, f32);
            hbits[r] = f2bf(ldG(h0, (j0 + r) * H1C + mcol, f32));
        }
        const int k = EE + mcol, kt = k >> 5, kg = (k & 31) >> 3, j = k & 7;
        #pragma unroll
        for (int r = 0; r < 4; r++) Af[0][kt][kg * 16 + r][j] = hbits[r];
    }
    if (xl) {
        int tok = toks[lr][t0];
        ushort_t v = f2bf(ldG(emb, tok * EE + kx, f32));
        const int kt = kx >> 5, kg = (kx & 31) >> 3, j = kx & 7;
        Af[0][kt][kg * 16 + lr][j] = v;
        tok = toks[lr][t0 + dt];
        xv = f2bf(ldG(emb, tok * EE + kx, f32));
    }

    for (int it = 0; it < SS; it++) {
        const int t = t0 + dt * it;
        const int cur = it & 1, nxt = cur ^ 1;
        __syncthreads();
        short8 af[2];
        #pragma unroll
        for (int kt = 0; kt < 2; kt++) af[kt] = *(const short8*)&Af[cur][kt][lane][0];
        if (xl && it + 2 < SS) {
            int tok = toks[lr][t + 2 * dt];
            xnv = f2bf(ldG(emb, tok * EE + kx, f32));
        }
        float4v acc[4];
        #pragma unroll
        for (int g = 0; g < 4; g++) {
            float4v a; a[0] = a[1] = a[2] = a[3] = bias_g[g];
            #pragma unroll
            for (int kt = 0; kt < 2; kt++) {
                a = __builtin_amdgcn_mfma_f32_16x16x32_bf16(af[kt], bhi[g][kt], a, 0, 0, 0);
                a = __builtin_amdgcn_mfma_f32_16x16x32_bf16(af[kt], blo[g][kt], a, 0, 0, 0);
            }
            acc[g] = a;
        }
        if (pw) {
            #pragma unroll
            for (int r = 0; r < 4; r++) {
                float gi = acc[0][r], gf = acc[1][r], gg = acc[2][r], go = acc[3][r];
                float c = sigf(gf) * creg[r] + sigf(gi) * tanh_(gg);
                float h = sigf(go) * tanh_(c);
                creg[r] = c;
                hbits[r] = f2bf(h);
                hs[(size_t)(j0 + r) * (SS * H1C) + (size_t)t * H1C + mcol] = hbits[r];
            }
            const int k = EE + mcol, kt = k >> 5, kg = (k & 31) >> 3, j = k & 7;
            #pragma unroll
            for (int r = 0; r < 4; r++) Af[nxt][kt][kg * 16 + r][j] = hbits[r];
        }
        if (xl) {
            const int kt = kx >> 5, kg = (kx & 31) >> 3, j = kx & 7;
            Af[nxt][kt][kg * 16 + lr][j] = xv;
            xv = xnv;
        }
    }
}

// =========================================================================================
// Layer 2: MFMA LSTM. 256 thr (4 waves), 4 l2-rows/WG, grid 256.
// K (pad 128): k<60 = x (hs1 concat), 60..109 = h, 110..127 = 0.  N: n = g*64 + mcol,
// wave w owns mcol block [16w, 16w+16).
// =========================================================================================
__global__ __launch_bounds__(256) void lstm2_kernel(
    const ushort_t* __restrict__ hs1f, const ushort_t* __restrict__ hs1b,
    const void* __restrict__ h0_f, const void* __restrict__ c0_f,
    const void* __restrict__ Wih_f, const void* __restrict__ Whh_f,
    const void* __restrict__ bih_f, const void* __restrict__ bhh_f,
    const void* __restrict__ h0_b, const void* __restrict__ c0_b,
    const void* __restrict__ Wih_b, const void* __restrict__ Whh_b,
    const void* __restrict__ bih_b, const void* __restrict__ bhh_b,
    ushort_t* __restrict__ hsf, ushort_t* __restrict__ hsb,
    const int* __restrict__ flags)
{
    const int f32 = flags[0];
    const int wg = blockIdx.x, dir = wg >> 7, cb = (wg & 127) << 2, tid = threadIdx.x;
    const int wave = tid >> 6, lane = tid & 63, li = lane & 15, kq = lane >> 4;

    const void* h0  = dir ? h0_b  : h0_f;
    const void* c0  = dir ? c0_b  : c0_f;
    const void* Wih = dir ? Wih_b : Wih_f;
    const void* Whh = dir ? Whh_b : Whh_f;
    const void* bih = dir ? bih_b : bih_f;
    const void* bhh = dir ? bhh_b : bhh_f;
    ushort_t* hs = dir ? hsb : hsf;

    __shared__ __align__(16) ushort_t Af[2][4][64][8];

    for (int idx = tid; idx < 2 * 4 * 64 * 8; idx += 256) ((ushort_t*)Af)[idx] = 0;

    const int mcol = wave * 16 + li;
    short8 bhi[4][4], blo[4][4];
    float bias_g[4];
    #pragma unroll
    for (int g = 0; g < 4; g++) {
        const int wrow = g * H2C + mcol;
        const bool nok = mcol < H2C;
        bias_g[g] = nok ? (ldG(bih, wrow, f32) + ldG(bhh, wrow, f32)) : 0.f;
        #pragma unroll
        for (int kt = 0; kt < 4; kt++) {
            short8 hi, lo;
            #pragma unroll
            for (int j = 0; j < 8; j++) {
                int k = kt * 32 + kq * 8 + j;
                float w = 0.f;
                if (nok) {
                    if (k < 2 * H1C) w = ldG(Wih, wrow * (2 * H1C) + k, f32);
                    else if (k < 2 * H1C + H2C) w = ldG(Whh, wrow * H2C + (k - 2 * H1C), f32);
                }
                ushort_t h = f2bf(w);
                hi[j] = (short)h;
                lo[j] = (short)f2bf(w - bf2f(h));
            }
            bhi[g][kt] = hi; blo[g][kt] = lo;
        }
    }

    const int t0 = dir ? SS - 1 : 0, dt = dir ? -1 : 1;
    const bool pw = (lane < 16) && (mcol < H2C);
    float creg[4];
    ushort_t hbits[4];
    const int kx = tid >> 2, lr = tid & 3;
    const bool xl = tid < 4 * 2 * H1C;   // 240 loader lanes
    ushort_t xv = 0, xnv = 0;

    __syncthreads();   // Af zero done

    if (pw) {
        #pragma unroll
        for (int r = 0; r < 4; r++) {
            creg[r]  = ldG(c0, (cb + r) * H2C + mcol, f32);
            hbits[r] = f2bf(ldG(h0, (cb + r) * H2C + mcol, f32));
        }
        const int k = 2 * H1C + mcol, kt = k >> 5, kg = (k & 31) >> 3, j = k & 7;
        #pragma unroll
        for (int r = 0; r < 4; r++) Af[0][kt][kg * 16 + r][j] = hbits[r];
    }
    if (xl) {
        ushort_t v = (kx < H1C)
            ? hs1f[(size_t)t0 * (SS * H1C) + (size_t)(cb + lr) * H1C + kx]
            : hs1b[(size_t)t0 * (SS * H1C) + (size_t)(SS - 1 - (cb + lr)) * H1C + (kx - H1C)];
        const int kt = kx >> 5, kg = (kx & 31) >> 3, j = kx & 7;
        Af[0][kt][kg * 16 + lr][j] = v;
        const int a1 = t0 + dt;
        xv = (kx < H1C)
            ? hs1f[(size_t)a1 * (SS * H1C) + (size_t)(cb + lr) * H1C + kx]
            : hs1b[(size_t)a1 * (SS * H1C) + (size_t)(SS - 1 - (cb + lr)) * H1C + (kx - H1C)];
    }

    for (int it = 0; it < SS; it++) {
        const int a = t0 + dt * it;
        const int cur = it & 1, nxt = cur ^ 1;
        __syncthreads();
        short8 af[4];
        #pragma unroll
        for (int kt = 0; kt < 4; kt++) af[kt] = *(const short8*)&Af[cur][kt][lane][0];
        if (xl && it + 2 < SS) {
            const int a2 = a + 2 * dt;
            xnv = (kx < H1C)
                ? hs1f[(size_t)a2 * (SS * H1C) + (size_t)(cb + lr) * H1C + kx]
                : hs1b[(size_t)a2 * (SS * H1C) + (size_t)(SS - 1 - (cb + lr)) * H1C + (kx - H1C)];
        }
        float4v acc[4];
        #pragma unroll
        for (int g = 0; g < 4; g++) {
            float4v v; v[0] = v[1] = v[2] = v[3] = bias_g[g];
            #pragma unroll
            for (int kt = 0; kt < 4; kt++) {
                v = __builtin_amdgcn_mfma_f32_16x16x32_bf16(af[kt], bhi[g][kt], v, 0, 0, 0);
                v = __builtin_amdgcn_mfma_f32_16x16x32_bf16(af[kt], blo[g][kt], v, 0, 0, 0);
            }
            acc[g] = v;
        }
        if (pw) {
            #pragma unroll
            for (int r = 0; r < 4; r++) {
                float gi = acc[0][r], gf = acc[1][r], gg = acc[2][r], go = acc[3][r];
                float c = sigf(gf) * creg[r] + sigf(gi) * tanh_(gg);
                float h = sigf(go) * tanh_(c);
                creg[r] = c;
                hbits[r] = f2bf(h);
                hs[(size_t)a * (SS * H2C) + (size_t)(cb + r) * H2C + mcol] = hbits[r];
            }
            const int k = 2 * H1C + mcol, kt = k >> 5, kg = (k & 31) >> 3, j = k & 7;
            #pragma unroll
            for (int r = 0; r < 4; r++) Af[nxt][kt][kg * 16 + r][j] = hbits[r];
        }
        if (xl) {
            const int kt = kx >> 5, kg = (kx & 31) >> 3, j = kx & 7;
            Af[nxt][kt][kg * 16 + lr][j] = xv;
            xv = xnv;
        }
    }
}

// =========================================================================================
// Final linear as MFMA GEMM: out[pair][n] = X[pair][0:100] @ lin_w[n][:]^T + lin_b.
// WG = 64 pairs (4 waves x 16 rows). K (pad 128): k<50 = f-part, 64..113 = b-part.
// =========================================================================================
__global__ __launch_bounds__(256) void lin_kernel(
    const ushort_t* __restrict__ hs2f, const ushort_t* __restrict__ hs2b,
    const void* __restrict__ lw, const void* __restrict__ lb,
    void* __restrict__ out, const int* __restrict__ flags)
{
    const int f32 = flags[0];
    const int tid = threadIdx.x, wave = tid >> 6, lane = tid & 63, li = lane & 15, kq = lane >> 4;

    __shared__ __align__(16) ushort_t Af[4][4][64][8];   // [waveblk][kt][lane][8]

    short8 bhi[3][4], blo[3][4];
    float biasv[3];
    #pragma unroll
    for (int nt = 0; nt < 3; nt++) {
        const int n = nt * 16 + li;
        const bool nok = n < NTC;
        biasv[nt] = nok ? ldG(lb, n, f32) : 0.f;
        #pragma unroll
        for (int kt = 0; kt < 4; kt++) {
            short8 hi, lo;
            #pragma unroll
            for (int j = 0; j < 8; j++) {
                int k = kt * 32 + kq * 8 + j;
                float w = 0.f;
                if (nok) {
                    if (k < H2C) w = ldG(lw, n * 100 + k, f32);
                    else if (k >= 64 && k < 64 + H2C) w = ldG(lw, n * 100 + 50 + (k - 64), f32);
                }
                ushort_t h = f2bf(w);
                hi[j] = (short)h;
                lo[j] = (short)f2bf(w - bf2f(h));
            }
            bhi[nt][kt] = hi; blo[nt][kt] = lo;
        }
    }

    const int P0 = blockIdx.x * 64;
    const int i = P0 >> 9, j0 = P0 & 511;
    const int pair = tid & 63, m = pair & 15, wb = pair >> 4;
    #pragma unroll
    for (int c = 0; c < 4; c++) {
        const int kg = (tid >> 6) + c * 4;   // 0..15
        const int kbase = kg * 8;
        short8 sv;
        #pragma unroll
        for (int j = 0; j < 8; j++) {
            const int k = kbase + j;
            ushort_t s = 0;
            if (k < H2C)
                s = hs2f[(size_t)i * (SS * H2C) + (size_t)(j0 + pair) * H2C + k];
            else if (k >= 64 && k < 64 + H2C)
                s = hs2b[(size_t)(SS - 1 - i) * (SS * H2C) + (size_t)(j0 + pair) * H2C + (k - 64)];
            sv[j] = (short)s;
        }
        const int kt = kg >> 2, kgrp = kg & 3;
        *(short8*)&Af[wb][kt][kgrp * 16 + m][0] = sv;
    }
    __syncthreads();

    short8 af[4];
    #pragma unroll
    for (int kt = 0; kt < 4; kt++) af[kt] = *(const short8*)&Af[wave][kt][lane][0];
    #pragma unroll
    for (int nt = 0; nt < 3; nt++) {
        float4v a; a[0] = a[1] = a[2] = a[3] = biasv[nt];
        #pragma unroll
        for (int kt = 0; kt < 4; kt++) {
            a = __builtin_amdgcn_mfma_f32_16x16x32_bf16(af[kt], bhi[nt][kt], a, 0, 0, 0);
            a = __builtin_amdgcn_mfma_f32_16x16x32_bf16(af[kt], blo[nt][kt], a, 0, 0, 0);
        }
        const int n = nt * 16 + li;
        if (n < NTC) {
            #pragma unroll
            for (int reg = 0; reg < 4; reg++) {
                const int prow = wave * 16 + kq * 4 + reg;   // local pair = C row
                const size_t op = (size_t)(P0 + prow) * NTC + n;
                if (f32) ((float*)out)[op] = a[reg];
                else     ((ushort_t*)out)[op] = f2bf(a[reg]);
            }
        }
    }
}

extern "C" void kernel_launch(void* const* d_in, const int* in_sizes, int n_in,
                              void* d_out, int out_size, void* d_ws, size_t ws_size,
                              hipStream_t stream)
{
    const void* x      = d_in[0];
    const void* emb_f1 = d_in[1];
    const void* emb_b1 = d_in[2];
    const void* h0_f1  = d_in[3];
    const void* c0_f1  = d_in[4];
    const void* Wih_f1 = d_in[5];
    const void* Whh_f1 = d_in[6];
    const void* bih_f1 = d_in[7];
    const void* bhh_f1 = d_in[8];
    const void* h0_b1  = d_in[9];
    const void* c0_b1  = d_in[10];
    const void* Wih_b1 = d_in[11];
    const void* Whh_b1 = d_in[12];
    const void* bih_b1 = d_in[13];
    const void* bhh_b1 = d_in[14];
    const void* h0_f2  = d_in[15];
    const void* c0_f2  = d_in[16];
    const void* Wih_f2 = d_in[17];
    const void* Whh_f2 = d_in[18];
    const void* bih_f2 = d_in[19];
    const void* bhh_f2 = d_in[20];
    const void* h0_b2  = d_in[21];
    const void* c0_b2  = d_in[22];
    const void* Wih_b2 = d_in[23];
    const void* Whh_b2 = d_in[24];
    const void* bih_b2 = d_in[25];
    const void* bhh_b2 = d_in[26];
    const void* lin_w  = d_in[27];
    const void* lin_b  = d_in[28];

    // ws layout: [flags: 256B] | hs1f | hs1b | hs2f | hs2b  (bf16, ~84 MB)
    int* flags = (int*)d_ws;
    ushort_t* hs1f = (ushort_t*)((char*)d_ws + 256);
    ushort_t* hs1b = hs1f + (size_t)BB * SS * H1C;
    ushort_t* hs2f = hs1b + (size_t)BB * SS * H1C;
    ushort_t* hs2b = hs2f + (size_t)BB * SS * H2C;

    detect_kernel<<<1, 64, 0, stream>>>(bih_f1, x, flags);
    lstm1_kernel<<<256, 128, 0, stream>>>(x, emb_f1, emb_b1,
        h0_f1, c0_f1, Wih_f1, Whh_f1, bih_f1, bhh_f1,
        h0_b1, c0_b1, Wih_b1, Whh_b1, bih_b1, bhh_b1, hs1f, hs1b, flags);
    lstm2_kernel<<<256, 256, 0, stream>>>(hs1f, hs1b,
        h0_f2, c0_f2, Wih_f2, Whh_f2, bih_f2, bhh_f2,
        h0_b2, c0_b2, Wih_b2, Whh_b2, bih_b2, bhh_b2, hs2f, hs2b, flags);
    lin_kernel<<<(BB * SS) / 64, 256, 0, stream>>>(hs2f, hs2b, lin_w, lin_b, d_out, flags);
}

// Round 4
// 1375.164 us; speedup vs baseline: 1.6384x; 1.0831x over previous
//
#include <hip/hip_runtime.h>
#include <hip/hip_bf16.h>

typedef __hip_bfloat16 bf16;
typedef __attribute__((ext_vector_type(8))) short short8;
typedef __attribute__((ext_vector_type(4))) float float4v;
typedef unsigned short ushort_t;

#define BB 512
#define SS 512
#define EE 20
#define H1C 30
#define H2C 50
#define NTC 45

// raw barrier: order LDS only; leave global loads in flight (no vmcnt drain)
#define BAR() asm volatile("s_waitcnt lgkmcnt(0)\n\ts_barrier" ::: "memory")

__device__ __forceinline__ float sigf(float v) { return 1.0f / (1.0f + __expf(-v)); }
__device__ __forceinline__ float tanh_(float v) { return 2.0f / (1.0f + __expf(-2.0f * v)) - 1.0f; }

__device__ __forceinline__ ushort_t f2bf(float f) {           // RNE f32->bf16 bits
    unsigned u = __float_as_uint(f);
    unsigned r = u + 0x7FFFu + ((u >> 16) & 1u);
    return (ushort_t)(r >> 16);
}
__device__ __forceinline__ float bf2f(ushort_t s) { return __uint_as_float(((unsigned)s) << 16); }

__device__ __forceinline__ float ldG(const void* p, int i, int f32) {
    if (f32) return ((const float*)p)[i];
    return bf2f(((const ushort_t*)p)[i]);
}
__device__ __forceinline__ int ldTok(const void* x, int i, int x64) {
    const int* xi = (const int*)x;
    return x64 ? xi[2 * i] : xi[i];
}

// ---------------- dtype detector: flags[0]=is_f32, flags[1]=is_x_int64 ----------------
__global__ void detect_kernel(const void* bih, const void* x, int* flags) {
    if (threadIdx.x == 0 && blockIdx.x == 0) {
        const ushort_t* u = (const ushort_t*)bih;
        int isf = 0;
        for (int i = 0; i < 120; i++) {
            float v = fabsf(bf2f(u[i]));
            if (!(v < 16.0f)) isf = 1;
        }
        flags[0] = isf;
        const int* xi = (const int*)x;
        int orv = 0;
        for (int i = 1; i < 32; i += 2) orv |= xi[i];
        flags[1] = (orv == 0) ? 1 : 0;
    }
}

struct XV4 { float v[4]; };

// =========================================================================================
// Layer 1. grid 64 (dir*32 + jblk), block 128 (2 waves). WG owns 16 batch rows.
// K pad 64: k<20 emb(x), 20..49 h, rest 0. N: per-gate pad 30->32; wave w owns col
// n = w*16+li of each gate (4 acc tiles = i,f,g,o). Af[buf][kt][kg*16+m][j], m=batch row.
// hs1P layout: [batch][t][32] bf16 (pad cols written as 0).
// =========================================================================================
__global__ __launch_bounds__(128) void lstm1_kernel(
    const void* __restrict__ x,
    const void* __restrict__ emb_f, const void* __restrict__ emb_b,
    const void* __restrict__ h0_f, const void* __restrict__ c0_f,
    const void* __restrict__ Wih_f, const void* __restrict__ Whh_f,
    const void* __restrict__ bih_f, const void* __restrict__ bhh_f,
    const void* __restrict__ h0_b, const void* __restrict__ c0_b,
    const void* __restrict__ Wih_b, const void* __restrict__ Whh_b,
    const void* __restrict__ bih_b, const void* __restrict__ bhh_b,
    ushort_t* __restrict__ hsf, ushort_t* __restrict__ hsb,
    const int* __restrict__ flags)
{
    const int f32v = flags[0], x64 = flags[1];
    const int wg = blockIdx.x, dir = wg >> 5, j0 = (wg & 31) << 4, tid = threadIdx.x;
    const int wave = tid >> 6, lane = tid & 63, li = lane & 15, quad = lane >> 4;

    const void* emb = dir ? emb_b : emb_f;
    const void* h0  = dir ? h0_b  : h0_f;
    const void* c0  = dir ? c0_b  : c0_f;
    const void* Wih = dir ? Wih_b : Wih_f;
    const void* Whh = dir ? Whh_b : Whh_f;
    const void* bih = dir ? bih_b : bih_f;
    const void* bhh = dir ? bhh_b : bhh_f;
    ushort_t* hs = dir ? hsb : hsf;

    __shared__ __align__(16) ushort_t Af[2][2][64][8];
    __shared__ int toks[16][SS];

    for (int idx = tid; idx < 16 * SS; idx += 128) {
        int r = idx >> 9, t = idx & (SS - 1);
        toks[r][t] = ldTok(x, (j0 + r) * SS + t, x64);
    }
    for (int idx = tid; idx < 2 * 2 * 64 * 8; idx += 128) ((ushort_t*)Af)[idx] = 0;

    const int n = wave * 16 + li;          // gate col / hidden idx (valid < 30)
    const bool nok = n < H1C;

    short8 bhi[4][2], blo[4][2];
    float bias_g[4];
    #pragma unroll
    for (int g = 0; g < 4; g++) {
        const int wrow = g * H1C + n;
        bias_g[g] = nok ? (ldG(bih, wrow, f32v) + ldG(bhh, wrow, f32v)) : 0.f;
        #pragma unroll
        for (int kt = 0; kt < 2; kt++) {
            short8 hi, lo;
            #pragma unroll
            for (int j = 0; j < 8; j++) {
                int k = kt * 32 + quad * 8 + j;
                float w = 0.f;
                if (nok) {
                    if (k < EE) w = ldG(Wih, wrow * EE + k, f32v);
                    else if (k < EE + H1C) w = ldG(Whh, wrow * H1C + (k - EE), f32v);
                }
                ushort_t h = f2bf(w);
                hi[j] = (short)h;
                lo[j] = (short)f2bf(w - bf2f(h));
            }
            bhi[g][kt] = hi; blo[g][kt] = lo;
        }
    }

    const int kh = EE + n;                               // h k-slot 20..51
    const int khk = kh >> 5, khg = (kh & 31) >> 3, khj = kh & 7;
    const int lrow = tid / 5, lc = tid - lrow * 5, k0 = lc * 4;   // loader (tid<80)
    const bool ldr = tid < 80;
    const int t0 = dir ? SS - 1 : 0, dt = dir ? -1 : 1;

    __syncthreads();   // toks + Af zero visible

    float creg[4];
    #pragma unroll
    for (int r = 0; r < 4; r++) {
        const int m = quad * 4 + r;
        creg[r] = nok ? ldG(c0, (j0 + m) * H1C + n, f32v) : 0.f;
        ushort_t hb = nok ? f2bf(ldG(h0, (j0 + m) * H1C + n, f32v)) : 0;
        Af[0][khk][khg * 16 + m][khj] = hb;
    }
    XV4 xA, xB;
    if (ldr) {
        int tok = toks[lrow][t0];
        #pragma unroll
        for (int jj = 0; jj < 4; jj++)
            Af[0][0][(k0 >> 3) * 16 + lrow][(k0 & 7) + jj] = f2bf(ldG(emb, tok * EE + k0 + jj, f32v));
        int tok1 = toks[lrow][t0 + dt];
        #pragma unroll
        for (int jj = 0; jj < 4; jj++) xA.v[jj] = ldG(emb, tok1 * EE + k0 + jj, f32v);
    }
    __syncthreads();   // Af[0] complete

    auto step = [&](int it, XV4& xin, XV4& xout) {
        const int t = t0 + dt * it;
        const int cur = it & 1, nxt = cur ^ 1;
        BAR();
        short8 af0 = *(const short8*)&Af[cur][0][lane][0];
        short8 af1 = *(const short8*)&Af[cur][1][lane][0];
        if (ldr && it + 2 < SS) {                       // prefetch x(t+2dt)
            int tok = toks[lrow][t + 2 * dt];
            #pragma unroll
            for (int jj = 0; jj < 4; jj++) xout.v[jj] = ldG(emb, tok * EE + k0 + jj, f32v);
        }
        float4v acc[4];
        #pragma unroll
        for (int g = 0; g < 4; g++) {
            float4v a; a[0] = a[1] = a[2] = a[3] = bias_g[g];
            a = __builtin_amdgcn_mfma_f32_16x16x32_bf16(af0, bhi[g][0], a, 0, 0, 0);
            a = __builtin_amdgcn_mfma_f32_16x16x32_bf16(af0, blo[g][0], a, 0, 0, 0);
            a = __builtin_amdgcn_mfma_f32_16x16x32_bf16(af1, bhi[g][1], a, 0, 0, 0);
            a = __builtin_amdgcn_mfma_f32_16x16x32_bf16(af1, blo[g][1], a, 0, 0, 0);
            acc[g] = a;
        }
        ushort_t hb[4];
        #pragma unroll
        for (int r = 0; r < 4; r++) {
            float gi = acc[0][r], gf = acc[1][r], gg = acc[2][r], go = acc[3][r];
            float c = sigf(gf) * creg[r] + sigf(gi) * tanh_(gg);
            float h = sigf(go) * tanh_(c);
            creg[r] = c;
            hb[r] = nok ? f2bf(h) : 0;
            hs[((size_t)(j0 + quad * 4 + r) * SS + t) * 32 + n] = hb[r];
        }
        if (it + 1 < SS) {
            #pragma unroll
            for (int r = 0; r < 4; r++) Af[nxt][khk][khg * 16 + quad * 4 + r][khj] = hb[r];
            if (ldr) {
                #pragma unroll
                for (int jj = 0; jj < 4; jj++)
                    Af[nxt][0][(k0 >> 3) * 16 + lrow][(k0 & 7) + jj] = f2bf(xin.v[jj]);
            }
        }
    };
    for (int it = 0; it < SS; it += 2) { step(it, xA, xB); step(it + 1, xB, xA); }
}

// =========================================================================================
// Layer 2. grid 64 (dir*32 + ablk), block 256 (4 waves). WG owns 16 l2-rows (a), steps c.
// x_c(a) = concat( hs1Pf[b=c][t=a][0..29], hs1Pb[b=c][t=511-a][0..29] ).
// K pad 128: k<32 f-x, 32..63 b-x, 64..113 h, rest 0. N 64-pad: wave w owns n=w*16+li.
// hs2T layout: [c][64][batch 512] bf16.
// =========================================================================================
__global__ __launch_bounds__(256) void lstm2_kernel(
    const ushort_t* __restrict__ hs1f, const ushort_t* __restrict__ hs1b,
    const void* __restrict__ h0_f, const void* __restrict__ c0_f,
    const void* __restrict__ Wih_f, const void* __restrict__ Whh_f,
    const void* __restrict__ bih_f, const void* __restrict__ bhh_f,
    const void* __restrict__ h0_b, const void* __restrict__ c0_b,
    const void* __restrict__ Wih_b, const void* __restrict__ Whh_b,
    const void* __restrict__ bih_b, const void* __restrict__ bhh_b,
    ushort_t* __restrict__ hsf, ushort_t* __restrict__ hsb,
    const int* __restrict__ flags)
{
    const int f32v = flags[0];
    const int wg = blockIdx.x, dir = wg >> 5, cb = (wg & 31) << 4, tid = threadIdx.x;
    const int wave = tid >> 6, lane = tid & 63, li = lane & 15, quad = lane >> 4;

    const void* h0  = dir ? h0_b  : h0_f;
    const void* c0  = dir ? c0_b  : c0_f;
    const void* Wih = dir ? Wih_b : Wih_f;
    const void* Whh = dir ? Whh_b : Whh_f;
    const void* bih = dir ? bih_b : bih_f;
    const void* bhh = dir ? bhh_b : bhh_f;
    ushort_t* hs = dir ? hsb : hsf;

    __shared__ __align__(16) ushort_t Af[2][4][64][8];
    for (int idx = tid; idx < 2 * 4 * 64 * 8; idx += 256) ((ushort_t*)Af)[idx] = 0;

    const int n = wave * 16 + li;          // gate col / hidden idx (valid < 50)
    const bool nok = n < H2C;

    short8 bhi[4][4], blo[4][4];
    float bias_g[4];
    #pragma unroll
    for (int g = 0; g < 4; g++) {
        const int wrow = g * H2C + n;
        bias_g[g] = nok ? (ldG(bih, wrow, f32v) + ldG(bhh, wrow, f32v)) : 0.f;
        #pragma unroll
        for (int kt = 0; kt < 4; kt++) {
            short8 hi, lo;
            #pragma unroll
            for (int j = 0; j < 8; j++) {
                int k = kt * 32 + quad * 8 + j;
                float w = 0.f;
                if (nok) {
                    if (k < H1C) w = ldG(Wih, wrow * (2 * H1C) + k, f32v);
                    else if (k >= 32 && k < 32 + H1C) w = ldG(Wih, wrow * (2 * H1C) + H1C + (k - 32), f32v);
                    else if (k >= 64 && k < 64 + H2C) w = ldG(Whh, wrow * H2C + (k - 64), f32v);
                }
                ushort_t h = f2bf(w);
                hi[j] = (short)h;
                lo[j] = (short)f2bf(w - bf2f(h));
            }
            bhi[g][kt] = hi; blo[g][kt] = lo;
        }
    }

    const int kh = 64 + n;                               // h k-slot 64..127
    const int khk = kh >> 5, khg = (kh & 31) >> 3, khj = kh & 7;
    const int lrow = tid >> 4, k0 = (tid & 15) * 4;      // loader: all 256 threads
    const int t0 = dir ? SS - 1 : 0, dt = dir ? -1 : 1;

    // x loader: value for step c, row a=cb+lrow, k-chunk k0 (0..60)
    auto loadX = [&](int c) -> ushort4 {
        const int a = cb + lrow;
        if (k0 < 32)
            return *(const ushort4*)&hs1f[((size_t)c * SS + a) * 32 + k0];
        else
            return *(const ushort4*)&hs1b[((size_t)c * SS + (SS - 1 - a)) * 32 + (k0 - 32)];
    };

    __syncthreads();   // Af zero visible

    float creg[4];
    #pragma unroll
    for (int r = 0; r < 4; r++) {
        const int m = quad * 4 + r;
        creg[r] = nok ? ldG(c0, (cb + m) * H2C + n, f32v) : 0.f;
        ushort_t hb = nok ? f2bf(ldG(h0, (cb + m) * H2C + n, f32v)) : 0;
        Af[0][khk][khg * 16 + m][khj] = hb;
    }
    {
        ushort4 xi = loadX(t0);
        const int kg = (k0 & 31) >> 3, kt = k0 >> 5, jb = k0 & 7;
        Af[0][kt][kg * 16 + lrow][jb + 0] = xi.x;
        Af[0][kt][kg * 16 + lrow][jb + 1] = xi.y;
        Af[0][kt][kg * 16 + lrow][jb + 2] = xi.z;
        Af[0][kt][kg * 16 + lrow][jb + 3] = xi.w;
    }
    ushort4 xA = loadX(t0 + dt), xB;
    __syncthreads();   // Af[0] complete

    auto step = [&](int it, ushort4& xin, ushort4& xout) {
        const int c = t0 + dt * it;
        const int cur = it & 1, nxt = cur ^ 1;
        BAR();
        short8 af[4];
        #pragma unroll
        for (int kt = 0; kt < 4; kt++) af[kt] = *(const short8*)&Af[cur][kt][lane][0];
        if (it + 2 < SS) xout = loadX(c + 2 * dt);       // prefetch
        float4v acc[4];
        #pragma unroll
        for (int g = 0; g < 4; g++) {
            float4v a; a[0] = a[1] = a[2] = a[3] = bias_g[g];
            #pragma unroll
            for (int kt = 0; kt < 4; kt++) {
                a = __builtin_amdgcn_mfma_f32_16x16x32_bf16(af[kt], bhi[g][kt], a, 0, 0, 0);
                a = __builtin_amdgcn_mfma_f32_16x16x32_bf16(af[kt], blo[g][kt], a, 0, 0, 0);
            }
            acc[g] = a;
        }
        ushort_t hb[4];
        #pragma unroll
        for (int r = 0; r < 4; r++) {
            float gi = acc[0][r], gf = acc[1][r], gg = acc[2][r], go = acc[3][r];
            float cc = sigf(gf) * creg[r] + sigf(gi) * tanh_(gg);
            float h = sigf(go) * tanh_(cc);
            creg[r] = cc;
            hb[r] = nok ? f2bf(h) : 0;
        }
        // hs2T[c][n][a]: 4 consecutive batch rows -> one 8B store
        ushort4 h4; h4.x = hb[0]; h4.y = hb[1]; h4.z = hb[2]; h4.w = hb[3];
        *(ushort4*)&hs[((size_t)c * 64 + n) * SS + cb + quad * 4] = h4;
        if (it + 1 < SS) {
            #pragma unroll
            for (int r = 0; r < 4; r++) Af[nxt][khk][khg * 16 + quad * 4 + r][khj] = hb[r];
            const int kg = (k0 & 31) >> 3, kt = k0 >> 5, jb = k0 & 7;
            Af[nxt][kt][kg * 16 + lrow][jb + 0] = xin.x;
            Af[nxt][kt][kg * 16 + lrow][jb + 1] = xin.y;
            Af[nxt][kt][kg * 16 + lrow][jb + 2] = xin.z;
            Af[nxt][kt][kg * 16 + lrow][jb + 3] = xin.w;
        }
    };
    for (int it = 0; it < SS; it += 2) { step(it, xA, xB); step(it + 1, xB, xA); }
}

// =========================================================================================
// Final linear (MFMA GEMM). out[i,j,:] = concat(hs2fT[i][:][j], hs2bT[511-i][:][j]) @ lw^T + lb
// WG = 64 pairs (fixed i, j-block of 64). K pad 128: k<50 f, 64..113 b.
// =========================================================================================
__global__ __launch_bounds__(256) void lin_kernel(
    const ushort_t* __restrict__ hs2f, const ushort_t* __restrict__ hs2b,
    const void* __restrict__ lw, const void* __restrict__ lb,
    void* __restrict__ out, const int* __restrict__ flags)
{
    const int f32v = flags[0];
    const int tid = threadIdx.x, wave = tid >> 6, lane = tid & 63, li = lane & 15, quad = lane >> 4;

    __shared__ __align__(16) ushort_t Af[4][4][64][8];   // [wb][kt][kg*16+row][j]
    for (int idx = tid; idx < 4 * 4 * 64 * 8; idx += 256) ((ushort_t*)Af)[idx] = 0;

    short8 bhi[3][4], blo[3][4];
    float biasv[3];
    #pragma unroll
    for (int nt = 0; nt < 3; nt++) {
        const int nn = nt * 16 + li;
        const bool nok = nn < NTC;
        biasv[nt] = nok ? ldG(lb, nn, f32v) : 0.f;
        #pragma unroll
        for (int kt = 0; kt < 4; kt++) {
            short8 hi, lo;
            #pragma unroll
            for (int j = 0; j < 8; j++) {
                int k = kt * 32 + quad * 8 + j;
                float w = 0.f;
                if (nok) {
                    if (k < H2C) w = ldG(lw, nn * 100 + k, f32v);
                    else if (k >= 64 && k < 64 + H2C) w = ldG(lw, nn * 100 + 50 + (k - 64), f32v);
                }
                ushort_t h = f2bf(w);
                hi[j] = (short)h;
                lo[j] = (short)f2bf(w - bf2f(h));
            }
            bhi[nt][kt] = hi; blo[nt][kt] = lo;
        }
    }

    const int P0 = blockIdx.x * 64;
    const int i = P0 >> 9, j0 = P0 & 511;
    __syncthreads();   // Af zero
    // stage X: 100 valid k-rows x 64 pairs
    for (int idx = tid; idx < 100 * 32; idx += 256) {
        const int kk = idx >> 5, pj = (idx & 31) * 2;
        unsigned v;
        int k;
        if (kk < H2C) {
            v = *(const unsigned*)&hs2f[((size_t)i * 64 + kk) * SS + j0 + pj];
            k = kk;
        } else {
            v = *(const unsigned*)&hs2b[((size_t)(SS - 1 - i) * 64 + (kk - H2C)) * SS + j0 + pj];
            k = 64 + (kk - H2C);
        }
        const int kt = k >> 5, kg = (k & 31) >> 3, j = k & 7;
        Af[pj >> 4][kt][kg * 16 + (pj & 15)][j] = (ushort_t)(v & 0xFFFF);
        Af[pj >> 4][kt][kg * 16 + ((pj + 1) & 15)][j] = (ushort_t)(v >> 16);
    }
    __syncthreads();

    short8 af[4];
    #pragma unroll
    for (int kt = 0; kt < 4; kt++) af[kt] = *(const short8*)&Af[wave][kt][lane][0];
    #pragma unroll
    for (int nt = 0; nt < 3; nt++) {
        float4v a; a[0] = a[1] = a[2] = a[3] = biasv[nt];
        #pragma unroll
        for (int kt = 0; kt < 4; kt++) {
            a = __builtin_amdgcn_mfma_f32_16x16x32_bf16(af[kt], bhi[nt][kt], a, 0, 0, 0);
            a = __builtin_amdgcn_mfma_f32_16x16x32_bf16(af[kt], blo[nt][kt], a, 0, 0, 0);
        }
        const int nn = nt * 16 + li;
        if (nn < NTC) {
            #pragma unroll
            for (int reg = 0; reg < 4; reg++) {
                const int prow = wave * 16 + quad * 4 + reg;
                const size_t op = (size_t)(P0 + prow) * NTC + nn;
                if (f32v) ((float*)out)[op] = a[reg];
                else      ((ushort_t*)out)[op] = f2bf(a[reg]);
            }
        }
    }
}

extern "C" void kernel_launch(void* const* d_in, const int* in_sizes, int n_in,
                              void* d_out, int out_size, void* d_ws, size_t ws_size,
                              hipStream_t stream)
{
    const void* x      = d_in[0];
    const void* emb_f1 = d_in[1];
    const void* emb_b1 = d_in[2];
    const void* h0_f1  = d_in[3];
    const void* c0_f1  = d_in[4];
    const void* Wih_f1 = d_in[5];
    const void* Whh_f1 = d_in[6];
    const void* bih_f1 = d_in[7];
    const void* bhh_f1 = d_in[8];
    const void* h0_b1  = d_in[9];
    const void* c0_b1  = d_in[10];
    const void* Wih_b1 = d_in[11];
    const void* Whh_b1 = d_in[12];
    const void* bih_b1 = d_in[13];
    const void* bhh_b1 = d_in[14];
    const void* h0_f2  = d_in[15];
    const void* c0_f2  = d_in[16];
    const void* Wih_f2 = d_in[17];
    const void* Whh_f2 = d_in[18];
    const void* bih_f2 = d_in[19];
    const void* bhh_f2 = d_in[20];
    const void* h0_b2  = d_in[21];
    const void* c0_b2  = d_in[22];
    const void* Wih_b2 = d_in[23];
    const void* Whh_b2 = d_in[24];
    const void* bih_b2 = d_in[25];
    const void* bhh_b2 = d_in[26];
    const void* lin_w  = d_in[27];
    const void* lin_b  = d_in[28];

    // ws: flags(256B) | hs1Pf | hs1Pb ([512][512][32] bf16 each, 16.8MB)
    //                 | hs2fT | hs2bT ([512][64][512] bf16 each, 33.6MB)   total ~101MB
    int* flags = (int*)d_ws;
    ushort_t* hs1f = (ushort_t*)((char*)d_ws + 256);
    ushort_t* hs1b = hs1f + (size_t)BB * SS * 32;
    ushort_t* hs2f = hs1b + (size_t)BB * SS * 32;
    ushort_t* hs2b = hs2f + (size_t)SS * 64 * BB;

    detect_kernel<<<1, 64, 0, stream>>>(bih_f1, x, flags);
    lstm1_kernel<<<64, 128, 0, stream>>>(x, emb_f1, emb_b1,
        h0_f1, c0_f1, Wih_f1, Whh_f1, bih_f1, bhh_f1,
        h0_b1, c0_b1, Wih_b1, Whh_b1, bih_b1, bhh_b1, hs1f, hs1b, flags);
    lstm2_kernel<<<64, 256, 0, stream>>>(hs1f, hs1b,
        h0_f2, c0_f2, Wih_f2, Whh_f2, bih_f2, bhh_f2,
        h0_b2, c0_b2, Wih_b2, Whh_b2, bih_b2, bhh_b2, hs2f, hs2b, flags);
    lin_kernel<<<(BB * SS) / 64, 256, 0, stream>>>(hs2f, hs2b, lin_w, lin_b, d_out, flags);
}

// Round 5
// 1002.844 us; speedup vs baseline: 2.2467x; 1.3713x over previous
//
#include <hip/hip_runtime.h>
#include <hip/hip_bf16.h>

typedef __hip_bfloat16 bf16;
typedef __attribute__((ext_vector_type(8))) short short8;
typedef __attribute__((ext_vector_type(4))) float float4v;
typedef unsigned short ushort_t;

#define BB 512
#define SS 512
#define EE 20
#define H1C 30
#define H2C 50
#define NTC 45

// raw barrier: order LDS only; leave global loads in flight (no vmcnt drain)
#define BAR() asm volatile("s_waitcnt lgkmcnt(0)\n\ts_barrier" ::: "memory")

// single-instruction transcendentals (v_exp_f32 / v_rcp_f32), ~1 ulp:
// avoids the IEEE fp32 division sequence (~10 instrs + ~100 cyc chain each)
#if __has_builtin(__builtin_amdgcn_exp2f)
#define EXP2(x) __builtin_amdgcn_exp2f(x)
#else
#define EXP2(x) exp2f(x)
#endif
#if __has_builtin(__builtin_amdgcn_rcpf)
#define RCPF(x) __builtin_amdgcn_rcpf(x)
#else
#define RCPF(x) (1.0f / (x))
#endif

__device__ __forceinline__ float sigf(float v) {
    return RCPF(1.0f + EXP2(-1.4426950408889634f * v));
}
__device__ __forceinline__ float tanh_(float v) {
    return 2.0f * RCPF(1.0f + EXP2(-2.8853900817779268f * v)) - 1.0f;
}

__device__ __forceinline__ ushort_t f2bf(float f) {           // RNE f32->bf16 bits
    unsigned u = __float_as_uint(f);
    unsigned r = u + 0x7FFFu + ((u >> 16) & 1u);
    return (ushort_t)(r >> 16);
}
__device__ __forceinline__ float bf2f(ushort_t s) { return __uint_as_float(((unsigned)s) << 16); }

__device__ __forceinline__ float ldG(const void* p, int i, int f32) {
    if (f32) return ((const float*)p)[i];
    return bf2f(((const ushort_t*)p)[i]);
}
__device__ __forceinline__ int ldTok(const void* x, int i, int x64) {
    const int* xi = (const int*)x;
    return x64 ? xi[2 * i] : xi[i];
}

// ---------------- dtype detector: flags[0]=is_f32, flags[1]=is_x_int64 ----------------
__global__ void detect_kernel(const void* bih, const void* x, int* flags) {
    if (threadIdx.x == 0 && blockIdx.x == 0) {
        const ushort_t* u = (const ushort_t*)bih;
        int isf = 0;
        for (int i = 0; i < 120; i++) {
            float v = fabsf(bf2f(u[i]));
            if (!(v < 16.0f)) isf = 1;
        }
        flags[0] = isf;
        const int* xi = (const int*)x;
        int orv = 0;
        for (int i = 1; i < 32; i += 2) orv |= xi[i];
        flags[1] = (orv == 0) ? 1 : 0;
    }
}

struct XV4 { float v[4]; };

// =========================================================================================
// Layer 1. grid 64 (dir*32 + jblk), block 128 (2 waves). WG owns 16 batch rows.
// K pad 64: k<20 emb(x), 20..49 h, rest 0. N: per-gate pad 30->32; wave w owns col
// n = w*16+li of each gate (4 acc tiles = i,f,g,o). Af[buf][kt][kg*16+m][j], m=batch row.
// hs1P layout: [batch][t][32] bf16 (pad cols written as 0).
// =========================================================================================
__global__ __launch_bounds__(128) void lstm1_kernel(
    const void* __restrict__ x,
    const void* __restrict__ emb_f, const void* __restrict__ emb_b,
    const void* __restrict__ h0_f, const void* __restrict__ c0_f,
    const void* __restrict__ Wih_f, const void* __restrict__ Whh_f,
    const void* __restrict__ bih_f, const void* __restrict__ bhh_f,
    const void* __restrict__ h0_b, const void* __restrict__ c0_b,
    const void* __restrict__ Wih_b, const void* __restrict__ Whh_b,
    const void* __restrict__ bih_b, const void* __restrict__ bhh_b,
    ushort_t* __restrict__ hsf, ushort_t* __restrict__ hsb,
    const int* __restrict__ flags)
{
    const int f32v = flags[0], x64 = flags[1];
    const int wg = blockIdx.x, dir = wg >> 5, j0 = (wg & 31) << 4, tid = threadIdx.x;
    const int wave = tid >> 6, lane = tid & 63, li = lane & 15, quad = lane >> 4;

    const void* emb = dir ? emb_b : emb_f;
    const void* h0  = dir ? h0_b  : h0_f;
    const void* c0  = dir ? c0_b  : c0_f;
    const void* Wih = dir ? Wih_b : Wih_f;
    const void* Whh = dir ? Whh_b : Whh_f;
    const void* bih = dir ? bih_b : bih_f;
    const void* bhh = dir ? bhh_b : bhh_f;
    ushort_t* hs = dir ? hsb : hsf;

    __shared__ __align__(16) ushort_t Af[2][2][64][8];
    __shared__ int toks[16][SS];

    for (int idx = tid; idx < 16 * SS; idx += 128) {
        int r = idx >> 9, t = idx & (SS - 1);
        toks[r][t] = ldTok(x, (j0 + r) * SS + t, x64);
    }
    for (int idx = tid; idx < 2 * 2 * 64 * 8; idx += 128) ((ushort_t*)Af)[idx] = 0;

    const int n = wave * 16 + li;          // gate col / hidden idx (valid < 30)
    const bool nok = n < H1C;

    short8 bhi[4][2], blo[4][2];
    float bias_g[4];
    #pragma unroll
    for (int g = 0; g < 4; g++) {
        const int wrow = g * H1C + n;
        bias_g[g] = nok ? (ldG(bih, wrow, f32v) + ldG(bhh, wrow, f32v)) : 0.f;
        #pragma unroll
        for (int kt = 0; kt < 2; kt++) {
            short8 hi, lo;
            #pragma unroll
            for (int j = 0; j < 8; j++) {
                int k = kt * 32 + quad * 8 + j;
                float w = 0.f;
                if (nok) {
                    if (k < EE) w = ldG(Wih, wrow * EE + k, f32v);
                    else if (k < EE + H1C) w = ldG(Whh, wrow * H1C + (k - EE), f32v);
                }
                ushort_t h = f2bf(w);
                hi[j] = (short)h;
                lo[j] = (short)f2bf(w - bf2f(h));
            }
            bhi[g][kt] = hi; blo[g][kt] = lo;
        }
    }

    const int kh = EE + n;                               // h k-slot 20..51
    const int khk = kh >> 5, khg = (kh & 31) >> 3, khj = kh & 7;
    const int lrow = tid / 5, lc = tid - lrow * 5, k0 = lc * 4;   // loader (tid<80)
    const bool ldr = tid < 80;
    const int t0 = dir ? SS - 1 : 0, dt = dir ? -1 : 1;

    __syncthreads();   // toks + Af zero visible

    float creg[4];
    #pragma unroll
    for (int r = 0; r < 4; r++) {
        const int m = quad * 4 + r;
        creg[r] = nok ? ldG(c0, (j0 + m) * H1C + n, f32v) : 0.f;
        ushort_t hb = nok ? f2bf(ldG(h0, (j0 + m) * H1C + n, f32v)) : 0;
        Af[0][khk][khg * 16 + m][khj] = hb;
    }
    XV4 xA, xB;
    if (ldr) {
        int tok = toks[lrow][t0];
        #pragma unroll
        for (int jj = 0; jj < 4; jj++)
            Af[0][0][(k0 >> 3) * 16 + lrow][(k0 & 7) + jj] = f2bf(ldG(emb, tok * EE + k0 + jj, f32v));
        int tok1 = toks[lrow][t0 + dt];
        #pragma unroll
        for (int jj = 0; jj < 4; jj++) xA.v[jj] = ldG(emb, tok1 * EE + k0 + jj, f32v);
    }
    __syncthreads();   // Af[0] complete

    auto step = [&](int it, XV4& xin, XV4& xout) {
        const int t = t0 + dt * it;
        const int cur = it & 1, nxt = cur ^ 1;
        BAR();
        short8 af0 = *(const short8*)&Af[cur][0][lane][0];
        short8 af1 = *(const short8*)&Af[cur][1][lane][0];
        if (ldr && it + 2 < SS) {                       // prefetch x(t+2dt)
            int tok = toks[lrow][t + 2 * dt];
            #pragma unroll
            for (int jj = 0; jj < 4; jj++) xout.v[jj] = ldG(emb, tok * EE + k0 + jj, f32v);
        }
        float4v acc[4];
        #pragma unroll
        for (int g = 0; g < 4; g++) {
            float4v a; a[0] = a[1] = a[2] = a[3] = bias_g[g];
            a = __builtin_amdgcn_mfma_f32_16x16x32_bf16(af0, bhi[g][0], a, 0, 0, 0);
            a = __builtin_amdgcn_mfma_f32_16x16x32_bf16(af0, blo[g][0], a, 0, 0, 0);
            a = __builtin_amdgcn_mfma_f32_16x16x32_bf16(af1, bhi[g][1], a, 0, 0, 0);
            a = __builtin_amdgcn_mfma_f32_16x16x32_bf16(af1, blo[g][1], a, 0, 0, 0);
            acc[g] = a;
        }
        ushort_t hb[4];
        #pragma unroll
        for (int r = 0; r < 4; r++) {
            float gi = acc[0][r], gf = acc[1][r], gg = acc[2][r], go = acc[3][r];
            float c = sigf(gf) * creg[r] + sigf(gi) * tanh_(gg);
            float h = sigf(go) * tanh_(c);
            creg[r] = c;
            hb[r] = nok ? f2bf(h) : 0;
            hs[((size_t)(j0 + quad * 4 + r) * SS + t) * 32 + n] = hb[r];
        }
        if (it + 1 < SS) {
            #pragma unroll
            for (int r = 0; r < 4; r++) Af[nxt][khk][khg * 16 + quad * 4 + r][khj] = hb[r];
            if (ldr) {
                #pragma unroll
                for (int jj = 0; jj < 4; jj++)
                    Af[nxt][0][(k0 >> 3) * 16 + lrow][(k0 & 7) + jj] = f2bf(xin.v[jj]);
            }
        }
    };
    for (int it = 0; it < SS; it += 2) { step(it, xA, xB); step(it + 1, xB, xA); }
}

// =========================================================================================
// Layer 2. grid 64 (dir*32 + ablk), block 256 (4 waves). WG owns 16 l2-rows (a), steps c.
// x_c(a) = concat( hs1Pf[b=c][t=a][0..29], hs1Pb[b=c][t=511-a][0..29] ).
// K pad 128: k<32 f-x, 32..63 b-x, 64..113 h, rest 0. N 64-pad: wave w owns n=w*16+li.
// hs2T layout: [c][64][batch 512] bf16.
// =========================================================================================
__global__ __launch_bounds__(256) void lstm2_kernel(
    const ushort_t* __restrict__ hs1f, const ushort_t* __restrict__ hs1b,
    const void* __restrict__ h0_f, const void* __restrict__ c0_f,
    const void* __restrict__ Wih_f, const void* __restrict__ Whh_f,
    const void* __restrict__ bih_f, const void* __restrict__ bhh_f,
    const void* __restrict__ h0_b, const void* __restrict__ c0_b,
    const void* __restrict__ Wih_b, const void* __restrict__ Whh_b,
    const void* __restrict__ bih_b, const void* __restrict__ bhh_b,
    ushort_t* __restrict__ hsf, ushort_t* __restrict__ hsb,
    const int* __restrict__ flags)
{
    const int f32v = flags[0];
    const int wg = blockIdx.x, dir = wg >> 5, cb = (wg & 31) << 4, tid = threadIdx.x;
    const int wave = tid >> 6, lane = tid & 63, li = lane & 15, quad = lane >> 4;

    const void* h0  = dir ? h0_b  : h0_f;
    const void* c0  = dir ? c0_b  : c0_f;
    const void* Wih = dir ? Wih_b : Wih_f;
    const void* Whh = dir ? Whh_b : Whh_f;
    const void* bih = dir ? bih_b : bih_f;
    const void* bhh = dir ? bhh_b : bhh_f;
    ushort_t* hs = dir ? hsb : hsf;

    __shared__ __align__(16) ushort_t Af[2][4][64][8];
    for (int idx = tid; idx < 2 * 4 * 64 * 8; idx += 256) ((ushort_t*)Af)[idx] = 0;

    const int n = wave * 16 + li;          // gate col / hidden idx (valid < 50)
    const bool nok = n < H2C;

    short8 bhi[4][4], blo[4][4];
    float bias_g[4];
    #pragma unroll
    for (int g = 0; g < 4; g++) {
        const int wrow = g * H2C + n;
        bias_g[g] = nok ? (ldG(bih, wrow, f32v) + ldG(bhh, wrow, f32v)) : 0.f;
        #pragma unroll
        for (int kt = 0; kt < 4; kt++) {
            short8 hi, lo;
            #pragma unroll
            for (int j = 0; j < 8; j++) {
                int k = kt * 32 + quad * 8 + j;
                float w = 0.f;
                if (nok) {
                    if (k < H1C) w = ldG(Wih, wrow * (2 * H1C) + k, f32v);
                    else if (k >= 32 && k < 32 + H1C) w = ldG(Wih, wrow * (2 * H1C) + H1C + (k - 32), f32v);
                    else if (k >= 64 && k < 64 + H2C) w = ldG(Whh, wrow * H2C + (k - 64), f32v);
                }
                ushort_t h = f2bf(w);
                hi[j] = (short)h;
                lo[j] = (short)f2bf(w - bf2f(h));
            }
            bhi[g][kt] = hi; blo[g][kt] = lo;
        }
    }

    const int kh = 64 + n;                               // h k-slot 64..127
    const int khk = kh >> 5, khg = (kh & 31) >> 3, khj = kh & 7;
    const int lrow = tid >> 4, k0 = (tid & 15) * 4;      // loader: all 256 threads
    const int t0 = dir ? SS - 1 : 0, dt = dir ? -1 : 1;

    // x loader: value for step c, row a=cb+lrow, k-chunk k0 (0..60)
    auto loadX = [&](int c) -> ushort4 {
        const int a = cb + lrow;
        if (k0 < 32)
            return *(const ushort4*)&hs1f[((size_t)c * SS + a) * 32 + k0];
        else
            return *(const ushort4*)&hs1b[((size_t)c * SS + (SS - 1 - a)) * 32 + (k0 - 32)];
    };

    __syncthreads();   // Af zero visible

    float creg[4];
    #pragma unroll
    for (int r = 0; r < 4; r++) {
        const int m = quad * 4 + r;
        creg[r] = nok ? ldG(c0, (cb + m) * H2C + n, f32v) : 0.f;
        ushort_t hb = nok ? f2bf(ldG(h0, (cb + m) * H2C + n, f32v)) : 0;
        Af[0][khk][khg * 16 + m][khj] = hb;
    }
    {
        ushort4 xi = loadX(t0);
        const int kg = (k0 & 31) >> 3, kt = k0 >> 5, jb = k0 & 7;
        Af[0][kt][kg * 16 + lrow][jb + 0] = xi.x;
        Af[0][kt][kg * 16 + lrow][jb + 1] = xi.y;
        Af[0][kt][kg * 16 + lrow][jb + 2] = xi.z;
        Af[0][kt][kg * 16 + lrow][jb + 3] = xi.w;
    }
    ushort4 xA = loadX(t0 + dt), xB;
    __syncthreads();   // Af[0] complete

    auto step = [&](int it, ushort4& xin, ushort4& xout) {
        const int c = t0 + dt * it;
        const int cur = it & 1, nxt = cur ^ 1;
        BAR();
        short8 af[4];
        #pragma unroll
        for (int kt = 0; kt < 4; kt++) af[kt] = *(const short8*)&Af[cur][kt][lane][0];
        if (it + 2 < SS) xout = loadX(c + 2 * dt);       // prefetch
        float4v acc[4];
        #pragma unroll
        for (int g = 0; g < 4; g++) {
            float4v a; a[0] = a[1] = a[2] = a[3] = bias_g[g];
            #pragma unroll
            for (int kt = 0; kt < 4; kt++) {
                a = __builtin_amdgcn_mfma_f32_16x16x32_bf16(af[kt], bhi[g][kt], a, 0, 0, 0);
                a = __builtin_amdgcn_mfma_f32_16x16x32_bf16(af[kt], blo[g][kt], a, 0, 0, 0);
            }
            acc[g] = a;
        }
        ushort_t hb[4];
        #pragma unroll
        for (int r = 0; r < 4; r++) {
            float gi = acc[0][r], gf = acc[1][r], gg = acc[2][r], go = acc[3][r];
            float cc = sigf(gf) * creg[r] + sigf(gi) * tanh_(gg);
            float h = sigf(go) * tanh_(cc);
            creg[r] = cc;
            hb[r] = nok ? f2bf(h) : 0;
        }
        // hs2T[c][n][a]: 4 consecutive batch rows -> one 8B store
        ushort4 h4; h4.x = hb[0]; h4.y = hb[1]; h4.z = hb[2]; h4.w = hb[3];
        *(ushort4*)&hs[((size_t)c * 64 + n) * SS + cb + quad * 4] = h4;
        if (it + 1 < SS) {
            #pragma unroll
            for (int r = 0; r < 4; r++) Af[nxt][khk][khg * 16 + quad * 4 + r][khj] = hb[r];
            const int kg = (k0 & 31) >> 3, kt = k0 >> 5, jb = k0 & 7;
            Af[nxt][kt][kg * 16 + lrow][jb + 0] = xin.x;
            Af[nxt][kt][kg * 16 + lrow][jb + 1] = xin.y;
            Af[nxt][kt][kg * 16 + lrow][jb + 2] = xin.z;
            Af[nxt][kt][kg * 16 + lrow][jb + 3] = xin.w;
        }
    };
    for (int it = 0; it < SS; it += 2) { step(it, xA, xB); step(it + 1, xB, xA); }
}

// =========================================================================================
// Final linear (MFMA GEMM). out[i,j,:] = concat(hs2fT[i][:][j], hs2bT[511-i][:][j]) @ lw^T + lb
// WG = 64 pairs (fixed i, j-block of 64). K pad 128: k<50 f, 64..113 b.
// =========================================================================================
__global__ __launch_bounds__(256) void lin_kernel(
    const ushort_t* __restrict__ hs2f, const ushort_t* __restrict__ hs2b,
    const void* __restrict__ lw, const void* __restrict__ lb,
    void* __restrict__ out, const int* __restrict__ flags)
{
    const int f32v = flags[0];
    const int tid = threadIdx.x, wave = tid >> 6, lane = tid & 63, li = lane & 15, quad = lane >> 4;

    __shared__ __align__(16) ushort_t Af[4][4][64][8];   // [wb][kt][kg*16+row][j]
    for (int idx = tid; idx < 4 * 4 * 64 * 8; idx += 256) ((ushort_t*)Af)[idx] = 0;

    short8 bhi[3][4], blo[3][4];
    float biasv[3];
    #pragma unroll
    for (int nt = 0; nt < 3; nt++) {
        const int nn = nt * 16 + li;
        const bool nok = nn < NTC;
        biasv[nt] = nok ? ldG(lb, nn, f32v) : 0.f;
        #pragma unroll
        for (int kt = 0; kt < 4; kt++) {
            short8 hi, lo;
            #pragma unroll
            for (int j = 0; j < 8; j++) {
                int k = kt * 32 + quad * 8 + j;
                float w = 0.f;
                if (nok) {
                    if (k < H2C) w = ldG(lw, nn * 100 + k, f32v);
                    else if (k >= 64 && k < 64 + H2C) w = ldG(lw, nn * 100 + 50 + (k - 64), f32v);
                }
                ushort_t h = f2bf(w);
                hi[j] = (short)h;
                lo[j] = (short)f2bf(w - bf2f(h));
            }
            bhi[nt][kt] = hi; blo[nt][kt] = lo;
        }
    }

    const int P0 = blockIdx.x * 64;
    const int i = P0 >> 9, j0 = P0 & 511;
    __syncthreads();   // Af zero
    // stage X: 100 valid k-rows x 64 pairs
    for (int idx = tid; idx < 100 * 32; idx += 256) {
        const int kk = idx >> 5, pj = (idx & 31) * 2;
        unsigned v;
        int k;
        if (kk < H2C) {
            v = *(const unsigned*)&hs2f[((size_t)i * 64 + kk) * SS + j0 + pj];
            k = kk;
        } else {
            v = *(const unsigned*)&hs2b[((size_t)(SS - 1 - i) * 64 + (kk - H2C)) * SS + j0 + pj];
            k = 64 + (kk - H2C);
        }
        const int kt = k >> 5, kg = (k & 31) >> 3, j = k & 7;
        Af[pj >> 4][kt][kg * 16 + (pj & 15)][j] = (ushort_t)(v & 0xFFFF);
        Af[pj >> 4][kt][kg * 16 + ((pj + 1) & 15)][j] = (ushort_t)(v >> 16);
    }
    __syncthreads();

    short8 af[4];
    #pragma unroll
    for (int kt = 0; kt < 4; kt++) af[kt] = *(const short8*)&Af[wave][kt][lane][0];
    #pragma unroll
    for (int nt = 0; nt < 3; nt++) {
        float4v a; a[0] = a[1] = a[2] = a[3] = biasv[nt];
        #pragma unroll
        for (int kt = 0; kt < 4; kt++) {
            a = __builtin_amdgcn_mfma_f32_16x16x32_bf16(af[kt], bhi[nt][kt], a, 0, 0, 0);
            a = __builtin_amdgcn_mfma_f32_16x16x32_bf16(af[kt], blo[nt][kt], a, 0, 0, 0);
        }
        const int nn = nt * 16 + li;
        if (nn < NTC) {
            #pragma unroll
            for (int reg = 0; reg < 4; reg++) {
                const int prow = wave * 16 + quad * 4 + reg;
                const size_t op = (size_t)(P0 + prow) * NTC + nn;
                if (f32v) ((float*)out)[op] = a[reg];
                else      ((ushort_t*)out)[op] = f2bf(a[reg]);
            }
        }
    }
}

extern "C" void kernel_launch(void* const* d_in, const int* in_sizes, int n_in,
                              void* d_out, int out_size, void* d_ws, size_t ws_size,
                              hipStream_t stream)
{
    const void* x      = d_in[0];
    const void* emb_f1 = d_in[1];
    const void* emb_b1 = d_in[2];
    const void* h0_f1  = d_in[3];
    const void* c0_f1  = d_in[4];
    const void* Wih_f1 = d_in[5];
    const void* Whh_f1 = d_in[6];
    const void* bih_f1 = d_in[7];
    const void* bhh_f1 = d_in[8];
    const void* h0_b1  = d_in[9];
    const void* c0_b1  = d_in[10];
    const void* Wih_b1 = d_in[11];
    const void* Whh_b1 = d_in[12];
    const void* bih_b1 = d_in[13];
    const void* bhh_b1 = d_in[14];
    const void* h0_f2  = d_in[15];
    const void* c0_f2  = d_in[16];
    const void* Wih_f2 = d_in[17];
    const void* Whh_f2 = d_in[18];
    const void* bih_f2 = d_in[19];
    const void* bhh_f2 = d_in[20];
    const void* h0_b2  = d_in[21];
    const void* c0_b2  = d_in[22];
    const void* Wih_b2 = d_in[23];
    const void* Whh_b2 = d_in[24];
    const void* bih_b2 = d_in[25];
    const void* bhh_b2 = d_in[26];
    const void* lin_w  = d_in[27];
    const void* lin_b  = d_in[28];

    // ws: flags(256B) | hs1Pf | hs1Pb ([512][512][32] bf16 each, 16.8MB)
    //                 | hs2fT | hs2bT ([512][64][512] bf16 each, 33.6MB)   total ~101MB
    int* flags = (int*)d_ws;
    ushort_t* hs1f = (ushort_t*)((char*)d_ws + 256);
    ushort_t* hs1b = hs1f + (size_t)BB * SS * 32;
    ushort_t* hs2f = hs1b + (size_t)BB * SS * 32;
    ushort_t* hs2b = hs2f + (size_t)SS * 64 * BB;

    detect_kernel<<<1, 64, 0, stream>>>(bih_f1, x, flags);
    lstm1_kernel<<<64, 128, 0, stream>>>(x, emb_f1, emb_b1,
        h0_f1, c0_f1, Wih_f1, Whh_f1, bih_f1, bhh_f1,
        h0_b1, c0_b1, Wih_b1, Whh_b1, bih_b1, bhh_b1, hs1f, hs1b, flags);
    lstm2_kernel<<<64, 256, 0, stream>>>(hs1f, hs1b,
        h0_f2, c0_f2, Wih_f2, Whh_f2, bih_f2, bhh_f2,
        h0_b2, c0_b2, Wih_b2, Whh_b2, bih_b2, bhh_b2, hs2f, hs2b, flags);
    lin_kernel<<<(BB * SS) / 64, 256, 0, stream>>>(hs2f, hs2b, lin_w, lin_b, d_out, flags);
}